// Round 5
// baseline (2865.733 us; speedup 1.0000x reference)
//
#include <hip/hip_runtime.h>

#define NT 1024
#define TSEQ 512

typedef float float2v __attribute__((ext_vector_type(2)));

__device__ __forceinline__ float sigmoid_(float x) { return 1.0f / (1.0f + __expf(-x)); }
__device__ __forceinline__ float tanh_(float x) { return 1.0f - 2.0f / (1.0f + __expf(2.0f * x)); }

// LDS-visibility-only barrier (validated rounds 2-4): drains lgkmcnt (ds ops)
// but NOT vmcnt, so global prefetch loads / h-stores stay in flight.
__device__ __forceinline__ void wg_barrier() {
    asm volatile("s_waitcnt lgkmcnt(0)" ::: "memory");
    __builtin_amdgcn_s_barrier();
}

// ---------------- prep kernel ----------------
// wbuf float4 index: (l*20 + g*5 + q)*1024 + tid -> W[g*100+rg][20f+4q .. +3]
// Padded K=200 row images with CLEAN x/h chunk split (20-k chunks):
//   layer0   : [x(5) 0(15) | h(100) @k20..119 | 0(80)]   -> f=0 pure-x, f in[1,6) h, f in[6,10) zero
//   layers>=1: [x(100) | h(100)]                          -> f in[0,5) x, f in[5,10) h
extern "C" __global__ void prep_weights(const float* __restrict__ Wih0,
                                        const float* __restrict__ Whh0,
                                        const float* __restrict__ WihL,
                                        const float* __restrict__ WhhL,
                                        float4* __restrict__ wbuf) {
    int gid = blockIdx.x * 256 + threadIdx.x;  // 5*20*1024 = 102400 total
    if (gid >= 102400) return;
    int tid = gid & 1023;
    int lgq = gid >> 10;
    int gq = lgq % 20;          // g*5 + q
    int l = lgq / 20;
    int g = gq / 5, q = gq % 5;
    float tmp[4] = {0.f, 0.f, 0.f, 0.f};
    if (tid < 1000) {
        int f = tid / 100, rg = tid % 100;
        int row = g * 100 + rg;
        int k0 = 20 * f + 4 * q;
        for (int c = 0; c < 4; ++c) {
            int k = k0 + c;
            float w = 0.f;
            if (l == 0) {
                if (k < 5) w = Wih0[row * 5 + k];
                else if (k >= 20 && k < 120) w = Whh0[row * 100 + (k - 20)];
            } else {
                if (k < 100) w = WihL[(l - 1) * 40000 + row * 100 + k];
                else w = WhhL[(l - 1) * 40000 + row * 100 + (k - 100)];
            }
            tmp[c] = w;
        }
    }
    wbuf[gid] = make_float4(tmp[0], tmp[1], tmp[2], tmp[3]);
}

// 8 packed FMAs (one k-quad, all 4 gates) against register weights w[40].
#define STEP_Q(Q, XQ) { float4 xq_ = (XQ); \
    float2v xlo = (float2v){xq_.x, xq_.y}; \
    float2v xhi = (float2v){xq_.z, xq_.w}; \
    a0 = __builtin_elementwise_fma(w[2*(Q)],      xlo, a0); \
    a0 = __builtin_elementwise_fma(w[2*(Q)+1],    xhi, a0); \
    a1 = __builtin_elementwise_fma(w[10+2*(Q)],   xlo, a1); \
    a1 = __builtin_elementwise_fma(w[10+2*(Q)+1], xhi, a1); \
    a2 = __builtin_elementwise_fma(w[20+2*(Q)],   xlo, a2); \
    a2 = __builtin_elementwise_fma(w[20+2*(Q)+1], xhi, a2); \
    a3 = __builtin_elementwise_fma(w[30+2*(Q)],   xlo, a3); \
    a3 = __builtin_elementwise_fma(w[30+2*(Q)+1], xhi, a3); }

// ---------------- main kernel ----------------
// Split-MAC pipeline, 2 barrier intervals per step:
//   I1: h-group (f>=5; L0 f>=1) h-MAC(t) from h(t-1); x-landers land x(t+2), issue x(t+3)
//   I2: x-group (f<5; L0 f==0) x-MAC(t+1) into part4x[(t+1)&1]
//       || combine(t) on tid 512..611 (h-group waves, disjoint from x-group)
// xh float layout: [xbuf0 0..99 | xbuf1 100..199 | h 200..299 | zero-pad 300..319]
template <bool FIRST, bool STORE>
__device__ void run_layer(const float4* __restrict__ wl, const float* __restrict__ bL,
                          const float* __restrict__ xsrc, float* __restrict__ hdst,
                          int b, int tid, int f, int rg, bool real,
                          float* xh, float4* part4h, float4* part4x) {
    // weights -> registers (branch-free, constant dest indices)
    float2v w[40];
#pragma unroll
    for (int g = 0; g < 4; ++g) {
#pragma unroll
        for (int q = 0; q < 5; ++q) {
            float4 t4 = wl[(g * 5 + q) * 1024 + tid];
            w[g * 10 + 2 * q]     = (float2v){t4.x, t4.y};
            w[g * 10 + 2 * q + 1] = (float2v){t4.z, t4.w};
        }
    }
    bool comb = (tid >= 512 && tid < 612);
    int cu = tid - 512;
    float bi = 0.f, bf = 0.f, bg = 0.f, bo = 0.f;
    if (comb) { bi = bL[cu]; bf = bL[100 + cu]; bg = bL[200 + cu]; bo = bL[300 + cu]; }

    bool xgrp = FIRST ? (f == 0) : (f < 5);
    // h-read base (float4 units) into xh; non-participants -> zero pad (base 75)
    int hb;
    if (FIRST) hb = (f >= 1 && f < 6) ? (50 + 5 * (f - 1)) : 75;
    else       hb = (f >= 5 && f < 10) ? (50 + 5 * (f - 5)) : 75;
    const float4* xhv = (const float4*)xh;
    int xoff = FIRST ? 0 : 5 * f;   // x-chunk offset within a parity buffer (f4 units)

    // zero xh (h region + pads + x tails)
    if (tid < 80) ((float4*)xh)[tid] = make_float4(0.f, 0.f, 0.f, 0.f);
    __syncthreads();
    // load x(0) -> xbuf0, x(1) -> xbuf1
    if (FIRST) {
        if (tid < 5) xh[tid] = xsrc[(size_t)b * TSEQ * 5 + tid];
        else if (tid >= 32 && tid < 37) xh[100 + (tid - 32)] = xsrc[((size_t)b * TSEQ + 1) * 5 + (tid - 32)];
    } else {
        const float4* s0 = (const float4*)xsrc + (size_t)b * TSEQ * 25;
        if (tid < 25) ((float4*)xh)[tid] = s0[tid];
        else if (tid >= 32 && tid < 57) ((float4*)xh)[25 + (tid - 32)] = s0[25 + (tid - 32)];
    }
    __syncthreads();   // full drain: prev-layer hseq stores + x rows visible

    // prologue: x-MAC(0) -> part4x[parity 0]  (first read is at I2(0), after bar1)
    if (xgrp) {
        float2v a0 = {0.f, 0.f}, a1 = {0.f, 0.f}, a2 = {0.f, 0.f}, a3 = {0.f, 0.f};
        const float4* xp = xhv + xoff;  // parity 0
#pragma unroll
        for (int q = 0; q < 5; ++q) STEP_Q(q, xp[q]);
        part4x[f * 100 + rg] = make_float4(a0.x + a0.y, a1.x + a1.y, a2.x + a2.y, a3.x + a3.y);
    }
    // landers (subset of x-group): issue x(2)
    bool lx = FIRST ? (tid < 5) : (tid < 25);
    float pfs = 0.f;
    float4 pf4 = {0.f, 0.f, 0.f, 0.f};
    if (lx) {
        if (FIRST) pfs = xsrc[((size_t)b * TSEQ + 2) * 5 + tid];
        else pf4 = ((const float4*)xsrc)[((size_t)b * TSEQ + 2) * 25 + tid];
    }

    float c = 0.f;

    for (int t = 0; t < TSEQ; ++t) {
        // ---- I1: land x(t+2) -> xbuf[t&1]; issue x(t+3); h-MAC(t) ----
        if (lx) {
            if (FIRST) xh[(t & 1) * 100 + tid] = pfs;
            else ((float4*)xh)[(t & 1) * 25 + tid] = pf4;
            int tn = (t + 3 <= TSEQ - 1) ? (t + 3) : (TSEQ - 1);
            if (FIRST) pfs = xsrc[((size_t)b * TSEQ + tn) * 5 + tid];
            else pf4 = ((const float4*)xsrc)[((size_t)b * TSEQ + tn) * 25 + tid];
        }
        if (!xgrp) {
            float2v a0 = {0.f, 0.f}, a1 = {0.f, 0.f}, a2 = {0.f, 0.f}, a3 = {0.f, 0.f};
            const float4* xp = xhv + hb;
#pragma unroll
            for (int q = 0; q < 5; ++q) STEP_Q(q, xp[q]);
            if (real) part4h[f * 100 + rg] = make_float4(a0.x + a0.y, a1.x + a1.y,
                                                         a2.x + a2.y, a3.x + a3.y);
        }
        wg_barrier();   // bar1: part4h + landed x visible

        // ---- I2: x-MAC(t+1)  ||  combine(t) ----
        if (xgrp) {
            if (t < TSEQ - 1) {
                float2v a0 = {0.f, 0.f}, a1 = {0.f, 0.f}, a2 = {0.f, 0.f}, a3 = {0.f, 0.f};
                const float4* xp = xhv + ((t + 1) & 1) * 25 + xoff;
#pragma unroll
                for (int q = 0; q < 5; ++q) STEP_Q(q, xp[q]);
                part4x[((t + 1) & 1) * 500 + f * 100 + rg] =
                    make_float4(a0.x + a0.y, a1.x + a1.y, a2.x + a2.y, a3.x + a3.y);
            }
        } else if (comb) {
            float4 s;
            if (FIRST) {
                s = part4h[100 + cu];
#pragma unroll
                for (int ff = 2; ff < 10; ++ff) {
                    float4 tt = part4h[ff * 100 + cu];
                    s.x += tt.x; s.y += tt.y; s.z += tt.z; s.w += tt.w;
                }
                float4 tx = part4x[(t & 1) * 500 + cu];
                s.x += tx.x; s.y += tx.y; s.z += tx.z; s.w += tx.w;
            } else {
                s = part4h[500 + cu];
#pragma unroll
                for (int ff = 6; ff < 10; ++ff) {
                    float4 tt = part4h[ff * 100 + cu];
                    s.x += tt.x; s.y += tt.y; s.z += tt.z; s.w += tt.w;
                }
#pragma unroll
                for (int ff = 0; ff < 5; ++ff) {
                    float4 tx = part4x[(t & 1) * 500 + ff * 100 + cu];
                    s.x += tx.x; s.y += tx.y; s.z += tx.z; s.w += tx.w;
                }
            }
            float gi = sigmoid_(s.x + bi);
            float gf = sigmoid_(s.y + bf);
            float gg = tanh_(s.z + bg);
            float go = sigmoid_(s.w + bo);
            c = gf * c + gi * gg;
            float hv = go * tanh_(c);
            xh[200 + cu] = hv;
            if (STORE) hdst[((size_t)b * TSEQ + t) * 100 + cu] = hv;  // fire-and-forget
        }
        wg_barrier();   // bar2: h(t) + part4x[(t+1)&1] visible
    }
}

#undef STEP_Q

extern "C" __global__ void __launch_bounds__(NT, 4)
gesture_lstm_kernel(const float* __restrict__ x,
                    const float4* __restrict__ wbuf,
                    const float* __restrict__ b0, const float* __restrict__ bLv,
                    const float* __restrict__ gamma, const float* __restrict__ beta,
                    const float* __restrict__ rmean, const float* __restrict__ rvar,
                    const float* __restrict__ W1, const float* __restrict__ b1,
                    const float* __restrict__ W2, const float* __restrict__ b2,
                    const float* __restrict__ W3, const float* __restrict__ b3,
                    float* __restrict__ out, float* __restrict__ hseq) {
    __shared__ __align__(16) float xh[320];
    __shared__ __align__(16) float4 part4h[1000];
    __shared__ __align__(16) float4 part4x[1000];   // [parity][500]
    __shared__ __align__(16) float hw[10000];

    int tid = threadIdx.x;
    int b = blockIdx.x;
    int f = tid / 100;   // 10 for dummies -> h-group, zero-pad reads, real=false
    int rg = tid % 100;
    bool real = tid < 1000;

    run_layer<true,  true >(wbuf + 0 * 20480, b0,         x,    hseq, b, tid, f, rg, real, xh, part4h, part4x);
    run_layer<false, true >(wbuf + 1 * 20480, bLv + 0,    hseq, hseq, b, tid, f, rg, real, xh, part4h, part4x);
    run_layer<false, true >(wbuf + 2 * 20480, bLv + 400,  hseq, hseq, b, tid, f, rg, real, xh, part4h, part4x);
    run_layer<false, true >(wbuf + 3 * 20480, bLv + 800,  hseq, hseq, b, tid, f, rg, real, xh, part4h, part4x);
    run_layer<false, false>(wbuf + 4 * 20480, bLv + 1200, hseq, hseq, b, tid, f, rg, real, xh, part4h, part4x);

    // ---- head: BN (inference) -> FC1+ReLU -> FC2+ReLU -> FC3 ----
    float* fcbuf = (float*)part4h;
    if (tid < 100) {
        float hv = xh[200 + tid];   // final h lives in the h region
        xh[tid] = (hv - rmean[tid]) * rsqrtf(rvar[tid] + 1e-5f) * gamma[tid] + beta[tid];
    }
    __syncthreads();

    for (int i = tid; i < 2500; i += NT) ((float4*)hw)[i] = ((const float4*)W1)[i];
    __syncthreads();
    if (tid < 100) {
        float acc = b1[tid];
#pragma unroll
        for (int k = 0; k < 100; ++k) acc = fmaf(hw[tid * 100 + k], xh[k], acc);
        fcbuf[tid] = fmaxf(acc, 0.0f);
    }
    __syncthreads();

    for (int i = tid; i < 2500; i += NT) ((float4*)hw)[i] = ((const float4*)W2)[i];
    __syncthreads();
    if (tid < 100) {
        float acc = b2[tid];
#pragma unroll
        for (int k = 0; k < 100; ++k) acc = fmaf(hw[tid * 100 + k], fcbuf[k], acc);
        fcbuf[400 + tid] = fmaxf(acc, 0.0f);
    }
    __syncthreads();

    if (tid < 3) {
        float acc = b3[tid];
#pragma unroll
        for (int k = 0; k < 100; ++k) acc = fmaf(W3[tid * 100 + k], fcbuf[400 + k], acc);
        out[b * 3 + tid] = acc;
    }
}

extern "C" void kernel_launch(void* const* d_in, const int* in_sizes, int n_in,
                              void* d_out, int out_size, void* d_ws, size_t ws_size,
                              hipStream_t stream) {
    const float* x     = (const float*)d_in[0];
    const float* Wih0  = (const float*)d_in[1];
    const float* Whh0  = (const float*)d_in[2];
    const float* b0    = (const float*)d_in[3];
    const float* WihL  = (const float*)d_in[4];
    const float* WhhL  = (const float*)d_in[5];
    const float* bLv   = (const float*)d_in[6];
    const float* gamma = (const float*)d_in[7];
    const float* beta  = (const float*)d_in[8];
    const float* rmean = (const float*)d_in[9];
    const float* rvar  = (const float*)d_in[10];
    const float* W1    = (const float*)d_in[11];
    const float* b1    = (const float*)d_in[12];
    const float* W2    = (const float*)d_in[13];
    const float* b2    = (const float*)d_in[14];
    const float* W3    = (const float*)d_in[15];
    const float* b3    = (const float*)d_in[16];

    float4* wbuf = (float4*)d_ws;                       // 102400 float4 = 1.6375 MB
    float* hseq  = (float*)((char*)d_ws + 102400 * 16); // 256*512*100 fp32 = 52.4 MB

    prep_weights<<<dim3(400), dim3(256), 0, stream>>>(Wih0, Whh0, WihL, WhhL, wbuf);
    gesture_lstm_kernel<<<dim3(256), dim3(NT), 0, stream>>>(
        x, wbuf, b0, bLv, gamma, beta, rmean, rvar, W1, b1, W2, b2, W3, b3,
        (float*)d_out, hseq);
}